// Round 8
// baseline (327.922 us; speedup 1.0000x reference)
//
#include <hip/hip_runtime.h>
#include <cstdint>
#include <cstddef>

#define T_TOK 2048
#define DMODEL 1024
#define NEXP 8
#define HID 2048
#define DUMP_ID 4096   // assignment-id for padding rows (token row 2048 = zeros)

typedef __bf16 bf16x8 __attribute__((ext_vector_type(8)));
typedef float f32x4 __attribute__((ext_vector_type(4)));
typedef unsigned short u16;
typedef u16 u16x8 __attribute__((ext_vector_type(8)));

__device__ __forceinline__ u16 f2bf(float f) {
    union { float f; unsigned int u; } v; v.f = f;
    unsigned int u = v.u;
    unsigned int r = (u + 0x7FFFu + ((u >> 16) & 1u)) >> 16;  // RNE
    return (u16)r;
}

__device__ __forceinline__ void gl2lds16(const void* g, void* l) {
    __builtin_amdgcn_global_load_lds(
        (const __attribute__((address_space(1))) void*)g,
        (__attribute__((address_space(3))) void*)l,
        16, 0, 0);
}

// ------------------------------------------------------------ fused_pre -----
// blocks [0, 256)  : router scores (one wave = 2 tokens, NO atomics) + x->bf16
// block  256       : zero xb dump row
__global__ __launch_bounds__(256) void fused_pre(
    const float4* __restrict__ x4, const float4* __restrict__ gw4,
    const float* __restrict__ bias, ushort4* __restrict__ xb4,
    unsigned int* __restrict__ selpack, float* __restrict__ w2,
    unsigned int* __restrict__ xb_dump_row_u32) {
    const int b = blockIdx.x;
    const int tid = threadIdx.x;

    if (b == 256) {                          // ---- zero dump token row ----
        if (tid < DMODEL / 2) xb_dump_row_u32[tid] = 0;
        return;
    }
    // ---- router: wave wv of router-block b handles tokens 2p, 2p+1 ----
    const int wv = tid >> 6;
    const int lane = tid & 63;
    const int pair = b * 4 + wv;             // 0..1023
    const int t0 = 2 * pair, t1 = t0 + 1;

    float acc0[NEXP], acc1[NEXP];
#pragma unroll
    for (int e = 0; e < NEXP; ++e) { acc0[e] = 0.f; acc1[e] = 0.f; }
#pragma unroll
    for (int j = 0; j < 4; ++j) {
        int i4 = lane + j * 64;              // float4 index within row (256/row)
        float4 a0 = x4[t0 * 256 + i4];
        float4 a1 = x4[t1 * 256 + i4];
        ushort4 s0, s1;
        s0.x = f2bf(a0.x); s0.y = f2bf(a0.y); s0.z = f2bf(a0.z); s0.w = f2bf(a0.w);
        s1.x = f2bf(a1.x); s1.y = f2bf(a1.y); s1.z = f2bf(a1.z); s1.w = f2bf(a1.w);
        xb4[t0 * 256 + i4] = s0;
        xb4[t1 * 256 + i4] = s1;
#pragma unroll
        for (int e = 0; e < NEXP; ++e) {
            float4 g = gw4[e * 256 + i4];
            acc0[e] += a0.x * g.x + a0.y * g.y + a0.z * g.z + a0.w * g.w;
            acc1[e] += a1.x * g.x + a1.y * g.y + a1.z * g.z + a1.w * g.w;
        }
    }
#pragma unroll
    for (int e = 0; e < NEXP; ++e)
        for (int off = 32; off > 0; off >>= 1) {
            acc0[e] += __shfl_xor(acc0[e], off, 64);
            acc1[e] += __shfl_xor(acc1[e], off, 64);
        }
    if (lane == 0) {
#pragma unroll
        for (int tt = 0; tt < 2; ++tt) {
            int t = tt ? t1 : t0;
            float sc[NEXP], bi[NEXP];
#pragma unroll
            for (int e = 0; e < NEXP; ++e) {
                float a = tt ? acc1[e] : acc0[e];
                sc[e] = 1.f / (1.f + expf(-a));
                bi[e] = sc[e] + bias[e];
            }
            int e0 = 0;
            for (int e = 1; e < NEXP; ++e) if (bi[e] > bi[e0]) e0 = e;  // ties->lowest
            int e1 = -1;
            for (int e = 0; e < NEXP; ++e) {
                if (e == e0) continue;
                if (e1 < 0 || bi[e] > bi[e1]) e1 = e;
            }
            selpack[t] = (unsigned int)e0 | ((unsigned int)e1 << 8);
            w2[2 * t]     = sc[e0] * sc[e0];
            w2[2 * t + 1] = sc[e1] * sc[e1];
        }
    }
}

// ------------------------------------------------------------ build_lists ---
// 8 blocks (one per expert), 256 threads: deterministic ballot-compaction.
__global__ __launch_bounds__(256) void build_lists(
    const unsigned int* __restrict__ selpack, int* __restrict__ counts,
    int* __restrict__ list) {
    const int e = blockIdx.x;
    const int tid = threadIdx.x;
    const int lane = tid & 63;
    const int wv = tid >> 6;
    __shared__ int wsum[4];
    __shared__ int base;
    if (tid == 0) base = 0;
    __syncthreads();
    for (int tb = 0; tb < T_TOK; tb += 256) {
        int t = tb + tid;
        unsigned int sp = selpack[t];
        bool f1 = ((sp >> 8) & 255u) == (unsigned)e;
        bool f = ((sp & 255u) == (unsigned)e) | f1;
        int id = 2 * t + (f1 ? 1 : 0);
        unsigned long long m = __ballot(f);
        int pos = __popcll(m & ((1ull << lane) - 1ull));
        if (lane == 0) wsum[wv] = __popcll(m);
        __syncthreads();
        int woff = 0;
#pragma unroll
        for (int i = 0; i < 4; ++i) if (i < wv) woff += wsum[i];
        int bse = base;
        if (f) list[e * T_TOK + bse + woff + pos] = id;
        __syncthreads();
        if (tid == 0) base = bse + wsum[0] + wsum[1] + wsum[2] + wsum[3];
    }
    __syncthreads();
    int total = base;
    if (tid == 0) counts[e] = total;
    for (int i = total + tid; i < T_TOK; i += 256) list[e * T_TOK + i] = DUMP_ID;
}

// ---------------------------------------------------- grouped GEMM ----------
// 128x128 tile, BK=128 (was 64): halves K-iterations, doubles per-iteration
// MFMA to amortize the exposed load latency (the measured bottleneck:
// MfmaUtil 9.6%, all pipes idle, latency-bound at 2 blocks/CU).
// MODE 0 (up):   A = xb gathered (row=id>>1, K=1024), B = w_up[e] fp32
//                epilogue: h[e*T+m0+row][n] = bf16( w2[id]*relu(v)^2 )
//                (h in LIST-POSITION order -> down-GEMM A is contiguous)
// MODE 1 (down): A = h (positions e*T+m0.., K=2048, contiguous),
//                B = w_down[e] fp32
//                epilogue: part[id][n] = v  (plain store; combine sums)
// A: gl2lds, linear LDS dest, XOR-pre-swizzled global source (16 chunks/row).
// B: fp32 reg-stage (16 dwordx4/thread, deep MLP) -> RNE cvt ->
//    XOR-swizzled ds_write_b128.
template <int MODE>
__global__ __launch_bounds__(256, 2) void moe_gemm(
    const u16* __restrict__ Asrc, const int* __restrict__ list,
    const int* __restrict__ counts, const float* __restrict__ Ball32,
    const float* __restrict__ w2, u16* __restrict__ Hout,
    float* __restrict__ Pout) {
    constexpr int K   = (MODE == 0) ? DMODEL : HID;   // 1024 / 2048
    constexpr int NKT = K / 128;                      // 8 / 16
    constexpr int NTN = ((MODE == 0) ? HID : DMODEL) / 128;  // 16 / 8
    constexpr int LOGNTN = (MODE == 0) ? 4 : 3;

    const int b = blockIdx.x;
    const int e = b & 7;                              // expert == XCD (b%8)
    const int rest = b >> 3;
    const int m0 = (rest >> LOGNTN) * 128;
    if (m0 >= counts[e]) return;
    const int n0 = (rest & (NTN - 1)) * 128;

    const int tid = threadIdx.x;
    const int lane = tid & 63;
    const int w = tid >> 6;

    __shared__ u16 As[128 * 128];                     // 32 KB
    __shared__ u16 Bs[128 * 128];                     // 32 KB

    const int* mylist = list + e * T_TOK + m0;
    const float* B32 = Ball32 + (size_t)e * HID * DMODEL;

    // A staging: 8 gl2lds calls; call c covers rows c*16+(tid>>4).
    // chunk index c16 = tid&15 (16B chunks, 16 per 128-elem row slice);
    // source pre-swizzled by gs = c16 ^ (row&7); LDS dest linear (tid*16B).
    const u16* ap[8];
    const int c16 = tid & 15;
#pragma unroll
    for (int c = 0; c < 8; ++c) {
        int row = c * 16 + (tid >> 4);
        int gs = c16 ^ (row & 7);
        int arow;
        if (MODE == 0) arow = mylist[row] >> 1;                 // gathered tokens
        else           arow = e * T_TOK + m0 + row;             // contiguous h
        ap[c] = Asrc + (size_t)arow * K + gs * 8;
    }
    // B staging: thread covers row = tid>>1, half bh = tid&1 (64 fp32).
    const int brow = tid >> 1;
    const int bh = tid & 1;
    const float4* bp = (const float4*)(B32 + (size_t)(n0 + brow) * K) + bh * 16;

    const int wm = (w >> 1) * 64;
    const int wn = (w & 1) * 64;
    const int quad = lane >> 4;
    const int lrow = lane & 15;

    f32x4 acc[4][4];
#pragma unroll
    for (int i = 0; i < 4; ++i)
#pragma unroll
        for (int j = 0; j < 4; ++j) acc[i][j] = f32x4{0.f, 0.f, 0.f, 0.f};

    for (int kt = 0; kt < NKT; ++kt) {
        // A: async global->LDS (linear dest = tid*16B within each 4KB slab)
#pragma unroll
        for (int c = 0; c < 8; ++c)
            gl2lds16(ap[c] + kt * 128, &As[c * 2048 + tid * 8]);
        // B: 16 independent dwordx4 -> regs (deep MLP), then cvt + swizzled write
        float4 bu[16];
#pragma unroll
        for (int j = 0; j < 16; ++j) bu[j] = bp[kt * 32 + j];
#pragma unroll
        for (int j = 0; j < 8; ++j) {
            u16x8 o;
            o[0] = f2bf(bu[2 * j].x);     o[1] = f2bf(bu[2 * j].y);
            o[2] = f2bf(bu[2 * j].z);     o[3] = f2bf(bu[2 * j].w);
            o[4] = f2bf(bu[2 * j + 1].x); o[5] = f2bf(bu[2 * j + 1].y);
            o[6] = f2bf(bu[2 * j + 1].z); o[7] = f2bf(bu[2 * j + 1].w);
            int c = bh * 8 + j;                                 // logical chunk
            *(u16x8*)&Bs[brow * 128 + (c ^ (brow & 7)) * 8] = o;
        }
        __syncthreads();  // drain staging
#pragma unroll
        for (int s = 0; s < 4; ++s) {                           // 16 chunks = 4 k-slices
            const int q = s * 4 + quad;
            bf16x8 af[4], bfr[4];
#pragma unroll
            for (int i = 0; i < 4; ++i) {
                int ra = wm + i * 16 + lrow;
                int rb = wn + i * 16 + lrow;
                af[i]  = *(const bf16x8*)&As[ra * 128 + (q ^ (ra & 7)) * 8];
                bfr[i] = *(const bf16x8*)&Bs[rb * 128 + (q ^ (rb & 7)) * 8];
            }
#pragma unroll
            for (int i = 0; i < 4; ++i)
#pragma unroll
                for (int j = 0; j < 4; ++j)
                    acc[i][j] = __builtin_amdgcn_mfma_f32_16x16x32_bf16(
                        af[i], bfr[j], acc[i][j], 0, 0, 0);
        }
        __syncthreads();  // protect LDS before next stage
    }

    // epilogue: C/D mapping col = lane&15, row = (lane>>4)*4 + reg
#pragma unroll
    for (int i = 0; i < 4; ++i) {
        int mbase = wm + i * 16 + (lane >> 4) * 4;
        int ids[4];
        float ww[4];
#pragma unroll
        for (int r = 0; r < 4; ++r) {
            ids[r] = mylist[mbase + r];
            if (MODE == 0) ww[r] = w2[ids[r]];
        }
#pragma unroll
        for (int j = 0; j < 4; ++j) {
            int n = n0 + wn + j * 16 + (lane & 15);
#pragma unroll
            for (int r = 0; r < 4; ++r) {
                float v = acc[i][j][r];
                if (MODE == 0) {
                    v = (v > 0.f) ? v * v * ww[r] : 0.f;   // pad rows: v==0 -> 0
                    Hout[(size_t)(e * T_TOK + m0 + mbase + r) * HID + n] = f2bf(v);
                } else {
                    if (ids[r] != DUMP_ID)
                        Pout[(size_t)ids[r] * DMODEL + n] = v;   // plain store
                }
            }
        }
    }
}

// ------------------------------------------------------------ combine -------
// out[t] = part[2t] + part[2t+1]   (2048 blocks x 256 thr x float4)
__global__ __launch_bounds__(256) void combine(
    const float4* __restrict__ part4, float4* __restrict__ out4) {
    int idx = blockIdx.x * 256 + threadIdx.x;     // [0, 524288)
    int t = idx >> 8;
    int d4 = idx & 255;
    float4 p0 = part4[(size_t)(2 * t) * 256 + d4];
    float4 p1 = part4[(size_t)(2 * t + 1) * 256 + d4];
    float4 o;
    o.x = p0.x + p1.x; o.y = p0.y + p1.y;
    o.z = p0.z + p1.z; o.w = p0.w + p1.w;
    out4[idx] = o;
}

// ---------------------------------------------------------------------------
extern "C" void kernel_launch(void* const* d_in, const int* in_sizes, int n_in,
                              void* d_out, int out_size, void* d_ws, size_t ws_size,
                              hipStream_t stream) {
    const float* x      = (const float*)d_in[0];
    const float* gate_w = (const float*)d_in[1];
    const float* w_up   = (const float*)d_in[2];
    const float* w_down = (const float*)d_in[3];
    const float* bias   = (const float*)d_in[4];
    float* out = (float*)d_out;

    // workspace layout (16B aligned chunks)
    char* p = (char*)d_ws;
    int* counts = (int*)p;                 p += 256;
    int* list   = (int*)p;                 p += NEXP * T_TOK * 4;
    float* w2   = (float*)p;               p += 4104 * 4;
    unsigned int* selpack = (unsigned int*)p;  p += T_TOK * 4;
    u16* xb  = (u16*)p;  p += (size_t)(T_TOK + 1) * DMODEL * 2;          // ~4 MB
    u16* h   = (u16*)p;  p += (size_t)NEXP * T_TOK * HID * 2;            // 64 MB
    float* part = (float*)p;  p += (size_t)2 * T_TOK * DMODEL * 4;       // 16 MB

    // 1. router scores + x->bf16 + dump-row init  (no output memset needed)
    fused_pre<<<257, 256, 0, stream>>>(
        (const float4*)x, (const float4*)gate_w, bias,
        (ushort4*)xb, selpack, w2,
        (unsigned int*)(xb + (size_t)T_TOK * DMODEL));

    // 2. deterministic list build (no global atomics)
    build_lists<<<NEXP, 256, 0, stream>>>(selpack, counts, list);

    // 3. up-GEMM: h(position-order) = bf16( w2 * relu(x @ Wu^T)^2 )
    moe_gemm<0><<<16 * (HID / 128) * NEXP, 256, 0, stream>>>(
        xb, list, counts, w_up, w2, h, nullptr);

    // 4. down-GEMM: part[id] = h_row @ Wd^T   (plain stores, no atomics)
    moe_gemm<1><<<16 * (DMODEL / 128) * NEXP, 256, 0, stream>>>(
        h, list, counts, w_down, w2, nullptr, part);

    // 5. combine: out[t] = part[2t] + part[2t+1]
    combine<<<T_TOK * DMODEL / 4 / 256, 256, 0, stream>>>(
        (const float4*)part, (float4*)out);
}

// Round 9
// 266.768 us; speedup vs baseline: 1.2292x; 1.2292x over previous
//
#include <hip/hip_runtime.h>
#include <cstdint>
#include <cstddef>

#define T_TOK 2048
#define DMODEL 1024
#define NEXP 8
#define HID 2048
#define DUMP_ID 4096   // assignment-id for padding rows (token row 2048 = zeros)

typedef __bf16 bf16x8 __attribute__((ext_vector_type(8)));
typedef float f32x4 __attribute__((ext_vector_type(4)));
typedef unsigned short u16;
typedef u16 u16x8 __attribute__((ext_vector_type(8)));

__device__ __forceinline__ u16 f2bf(float f) {
    union { float f; unsigned int u; } v; v.f = f;
    unsigned int u = v.u;
    unsigned int r = (u + 0x7FFFu + ((u >> 16) & 1u)) >> 16;  // RNE
    return (u16)r;
}

__device__ __forceinline__ void gl2lds16(const void* g, void* l) {
    __builtin_amdgcn_global_load_lds(
        (const __attribute__((address_space(1))) void*)g,
        (__attribute__((address_space(3))) void*)l,
        16, 0, 0);
}

// counted waits: never drain vmcnt to 0 in the main loop (T4)
#define WAITV(N) asm volatile("s_waitcnt vmcnt(" #N ")" ::: "memory")
#define LGKM0_BAR()                                            \
    do {                                                       \
        asm volatile("s_waitcnt lgkmcnt(0)" ::: "memory");     \
        __builtin_amdgcn_s_barrier();                          \
        __builtin_amdgcn_sched_barrier(0);                     \
    } while (0)

// ------------------------------------------------------------ fused_pre -----
// blocks [0, 256)  : router scores (one wave = 2 tokens, NO atomics) + x->bf16
// block  256       : zero xb dump row
__global__ __launch_bounds__(256) void fused_pre(
    const float4* __restrict__ x4, const float4* __restrict__ gw4,
    const float* __restrict__ bias, ushort4* __restrict__ xb4,
    unsigned int* __restrict__ selpack, float* __restrict__ w2,
    unsigned int* __restrict__ xb_dump_row_u32) {
    const int b = blockIdx.x;
    const int tid = threadIdx.x;

    if (b == 256) {                          // ---- zero dump token row ----
        if (tid < DMODEL / 2) xb_dump_row_u32[tid] = 0;
        return;
    }
    // ---- router: wave wv of router-block b handles tokens 2p, 2p+1 ----
    const int wv = tid >> 6;
    const int lane = tid & 63;
    const int pair = b * 4 + wv;             // 0..1023
    const int t0 = 2 * pair, t1 = t0 + 1;

    float acc0[NEXP], acc1[NEXP];
#pragma unroll
    for (int e = 0; e < NEXP; ++e) { acc0[e] = 0.f; acc1[e] = 0.f; }
#pragma unroll
    for (int j = 0; j < 4; ++j) {
        int i4 = lane + j * 64;              // float4 index within row (256/row)
        float4 a0 = x4[t0 * 256 + i4];
        float4 a1 = x4[t1 * 256 + i4];
        ushort4 s0, s1;
        s0.x = f2bf(a0.x); s0.y = f2bf(a0.y); s0.z = f2bf(a0.z); s0.w = f2bf(a0.w);
        s1.x = f2bf(a1.x); s1.y = f2bf(a1.y); s1.z = f2bf(a1.z); s1.w = f2bf(a1.w);
        xb4[t0 * 256 + i4] = s0;
        xb4[t1 * 256 + i4] = s1;
#pragma unroll
        for (int e = 0; e < NEXP; ++e) {
            float4 g = gw4[e * 256 + i4];
            acc0[e] += a0.x * g.x + a0.y * g.y + a0.z * g.z + a0.w * g.w;
            acc1[e] += a1.x * g.x + a1.y * g.y + a1.z * g.z + a1.w * g.w;
        }
    }
#pragma unroll
    for (int e = 0; e < NEXP; ++e)
        for (int off = 32; off > 0; off >>= 1) {
            acc0[e] += __shfl_xor(acc0[e], off, 64);
            acc1[e] += __shfl_xor(acc1[e], off, 64);
        }
    if (lane == 0) {
#pragma unroll
        for (int tt = 0; tt < 2; ++tt) {
            int t = tt ? t1 : t0;
            float sc[NEXP], bi[NEXP];
#pragma unroll
            for (int e = 0; e < NEXP; ++e) {
                float a = tt ? acc1[e] : acc0[e];
                sc[e] = 1.f / (1.f + expf(-a));
                bi[e] = sc[e] + bias[e];
            }
            int e0 = 0;
            for (int e = 1; e < NEXP; ++e) if (bi[e] > bi[e0]) e0 = e;  // ties->lowest
            int e1 = -1;
            for (int e = 0; e < NEXP; ++e) {
                if (e == e0) continue;
                if (e1 < 0 || bi[e] > bi[e1]) e1 = e;
            }
            selpack[t] = (unsigned int)e0 | ((unsigned int)e1 << 8);
            w2[2 * t]     = sc[e0] * sc[e0];
            w2[2 * t + 1] = sc[e1] * sc[e1];
        }
    }
}

// ------------------------------------------------------------ build_lists ---
// 8 blocks (one per expert), 256 threads: deterministic ballot-compaction.
__global__ __launch_bounds__(256) void build_lists(
    const unsigned int* __restrict__ selpack, int* __restrict__ counts,
    int* __restrict__ list) {
    const int e = blockIdx.x;
    const int tid = threadIdx.x;
    const int lane = tid & 63;
    const int wv = tid >> 6;
    __shared__ int wsum[4];
    __shared__ int base;
    if (tid == 0) base = 0;
    __syncthreads();
    for (int tb = 0; tb < T_TOK; tb += 256) {
        int t = tb + tid;
        unsigned int sp = selpack[t];
        bool f1 = ((sp >> 8) & 255u) == (unsigned)e;
        bool f = ((sp & 255u) == (unsigned)e) | f1;
        int id = 2 * t + (f1 ? 1 : 0);
        unsigned long long m = __ballot(f);
        int pos = __popcll(m & ((1ull << lane) - 1ull));
        if (lane == 0) wsum[wv] = __popcll(m);
        __syncthreads();
        int woff = 0;
#pragma unroll
        for (int i = 0; i < 4; ++i) if (i < wv) woff += wsum[i];
        int bse = base;
        if (f) list[e * T_TOK + bse + woff + pos] = id;
        __syncthreads();
        if (tid == 0) base = bse + wsum[0] + wsum[1] + wsum[2] + wsum[3];
    }
    __syncthreads();
    int total = base;
    if (tid == 0) counts[e] = total;
    for (int i = total + tid; i < T_TOK; i += 256) list[e * T_TOK + i] = DUMP_ID;
}

// ---------------------------------------------------- grouped GEMM ----------
// 128x128 tile, BK=64 (round-7 proven layout) + COUNTED-VMCNT 2-DEEP PIPELINE:
//   raw s_barrier (no implicit vmcnt(0) drain) + hand-counted s_waitcnt.
//   A: 3 LDS buffers (gl2lds, prefetch 2 K-steps ahead, mod-3 rotation).
//   B: 2 reg-sets (even/odd kt, statically indexed) + 2 LDS buffers.
//   Steady-state waits: vmcnt(16) before writeB (B(kt+1) retired, FIFO),
//   vmcnt(12) before barrier (own A(kt+1) gl2lds landed in LDS).
//   24 loads/thread in flight vs 12 with full drains -> higher achieved BW.
// MODE 0 (up):   A = xb gathered (row=id>>1, K=1024), B = w_up[e] fp32
//                epilogue: h[e*T+m0+row][n] = bf16( w2[id]*relu(v)^2 )
// MODE 1 (down): A = h (positions e*T+m0.., contiguous, K=2048),
//                B = w_down[e] fp32; epilogue: part[id][n] = v (plain store)
template <int MODE>
__global__ __launch_bounds__(256, 2) void moe_gemm(
    const u16* __restrict__ Asrc, const int* __restrict__ list,
    const int* __restrict__ counts, const float* __restrict__ Ball32,
    const float* __restrict__ w2, u16* __restrict__ Hout,
    float* __restrict__ Pout) {
    constexpr int K   = (MODE == 0) ? DMODEL : HID;   // 1024 / 2048
    constexpr int NKT = K / 64;                       // 16 / 32 (even)
    constexpr int NTN = ((MODE == 0) ? HID : DMODEL) / 128;  // 16 / 8
    constexpr int LOGNTN = (MODE == 0) ? 4 : 3;

    const int b = blockIdx.x;
    const int e = b & 7;                              // expert == XCD (b%8)
    const int rest = b >> 3;
    const int m0 = (rest >> LOGNTN) * 128;
    if (m0 >= counts[e]) return;
    const int n0 = (rest & (NTN - 1)) * 128;

    const int tid = threadIdx.x;
    const int lane = tid & 63;
    const int w = tid >> 6;

    __shared__ u16 As[3][128 * 64];                   // 48 KB
    __shared__ u16 Bs[2][128 * 64];                   // 32 KB  (80 KB total)

    const int* mylist = list + e * T_TOK + m0;
    const float* B32 = Ball32 + (size_t)e * HID * DMODEL;

    const u16* ap[4];
    const float4* bp[4];
    int bwr[4];
    const int c8 = tid & 7;                  // linear k-chunk this thread loads
#pragma unroll
    for (int it = 0; it < 4; ++it) {
        int row = it * 32 + (tid >> 3);
        int gs = c8 ^ (row & 7);
        if (MODE == 0) {
            int id = mylist[row];
            ap[it] = Asrc + (size_t)(id >> 1) * K + gs * 8;   // gathered tokens
        } else {
            ap[it] = Asrc + (size_t)(e * T_TOK + m0 + row) * K + gs * 8;  // contiguous
        }
        bp[it] = (const float4*)(B32 + (size_t)(n0 + row) * K) + c8 * 2;
        bwr[it] = row * 64 + gs * 8;                          // swizzled LDS dst
    }

    const int wm = (w >> 1) * 64;
    const int wn = (w & 1) * 64;
    const int quad = lane >> 4;
    const int lrow = lane & 15;

    f32x4 acc[4][4];
#pragma unroll
    for (int i = 0; i < 4; ++i)
#pragma unroll
        for (int j = 0; j < 4; ++j) acc[i][j] = f32x4{0.f, 0.f, 0.f, 0.f};

    float4 buE[4][2], buO[4][2];             // even/odd in-flight B reg-sets

#define ISSUE_A(KT)                                                          \
    do {                                                                     \
        u16* dst_ = &As[(KT) % 3][0];                                        \
        _Pragma("unroll")                                                    \
        for (int it_ = 0; it_ < 4; ++it_)                                    \
            gl2lds16(ap[it_] + (KT) * 64, dst_ + (it_ * 256 + w * 64) * 8);  \
    } while (0)

#define LOAD_B(KT, BU)                                                       \
    do {                                                                     \
        _Pragma("unroll")                                                    \
        for (int it_ = 0; it_ < 4; ++it_) {                                  \
            BU[it_][0] = bp[it_][(KT) * 16];                                 \
            BU[it_][1] = bp[it_][(KT) * 16 + 1];                             \
        }                                                                    \
    } while (0)

#define WRITE_B(KT, BU)                                                      \
    do {                                                                     \
        u16* dst_ = &Bs[(KT) & 1][0];                                        \
        _Pragma("unroll")                                                    \
        for (int it_ = 0; it_ < 4; ++it_) {                                  \
            u16x8 o_;                                                        \
            o_[0] = f2bf(BU[it_][0].x); o_[1] = f2bf(BU[it_][0].y);          \
            o_[2] = f2bf(BU[it_][0].z); o_[3] = f2bf(BU[it_][0].w);          \
            o_[4] = f2bf(BU[it_][1].x); o_[5] = f2bf(BU[it_][1].y);          \
            o_[6] = f2bf(BU[it_][1].z); o_[7] = f2bf(BU[it_][1].w);          \
            *(u16x8*)(dst_ + bwr[it_]) = o_;                                 \
        }                                                                    \
    } while (0)

    auto compute = [&](int kt) {
        const u16* As_ = &As[kt % 3][0];
        const u16* Bs_ = &Bs[kt & 1][0];
#pragma unroll
        for (int s = 0; s < 2; ++s) {
            const int q = s * 4 + quad;
            bf16x8 af[4], bfr[4];
#pragma unroll
            for (int i = 0; i < 4; ++i) {
                int ra = wm + i * 16 + lrow;
                int rb = wn + i * 16 + lrow;
                af[i]  = *(const bf16x8*)(As_ + ra * 64 + (q ^ (ra & 7)) * 8);
                bfr[i] = *(const bf16x8*)(Bs_ + rb * 64 + (q ^ (rb & 7)) * 8);
            }
#pragma unroll
            for (int i = 0; i < 4; ++i)
#pragma unroll
                for (int j = 0; j < 4; ++j)
                    acc[i][j] = __builtin_amdgcn_mfma_f32_16x16x32_bf16(
                        af[i], bfr[j], acc[i][j], 0, 0, 0);
        }
    };

    // ---- prologue: prefetch kt=0,1; publish tile 0 ----
    LOAD_B(0, buE);
    ISSUE_A(0);
    LOAD_B(1, buO);
    ISSUE_A(1);
    WAITV(12);            // B(0)+A(0) retired (first 12 of 24, FIFO)
    WRITE_B(0, buE);
    LGKM0_BAR();          // outstanding: B(1)=8 + A(1)=4 = 12 (invariant)

    // ---- main loop, unrolled x2 for static reg-set indexing ----
    for (int kt = 0; kt < NKT; kt += 2) {
        {   // even half: compute kt; B(kt+1) in buO; issue kt+2 into buE
            const bool i2 = (kt + 2 < NKT);
            if (i2) { LOAD_B(kt + 2, buE); ISSUE_A(kt + 2); }
            compute(kt);
            if (i2) WAITV(16); else WAITV(4);   // B(kt+1) retired
            WRITE_B(kt + 1, buO);               // kt+1 < NKT always here
            if (i2) WAITV(12); else WAITV(0);   // own A(kt+1) landed
            LGKM0_BAR();
        }
        {   // odd half: compute kt+1; B(kt+2) in buE; issue kt+3 into buO
            const int k1 = kt + 1;
            const bool i2 = (k1 + 2 < NKT);
            if (i2) { LOAD_B(k1 + 2, buO); ISSUE_A(k1 + 2); }
            compute(k1);
            if (i2) WAITV(16); else WAITV(4);
            if (k1 + 1 < NKT) WRITE_B(k1 + 1, buE);
            if (i2) WAITV(12); else WAITV(0);
            LGKM0_BAR();
        }
    }
#undef ISSUE_A
#undef LOAD_B
#undef WRITE_B

    // epilogue: C/D mapping col = lane&15, row = (lane>>4)*4 + reg
#pragma unroll
    for (int i = 0; i < 4; ++i) {
        int mbase = wm + i * 16 + (lane >> 4) * 4;
        int ids[4];
        float ww[4];
#pragma unroll
        for (int r = 0; r < 4; ++r) {
            ids[r] = mylist[mbase + r];
            if (MODE == 0) ww[r] = w2[ids[r]];
        }
#pragma unroll
        for (int j = 0; j < 4; ++j) {
            int n = n0 + wn + j * 16 + (lane & 15);
#pragma unroll
            for (int r = 0; r < 4; ++r) {
                float v = acc[i][j][r];
                if (MODE == 0) {
                    v = (v > 0.f) ? v * v * ww[r] : 0.f;   // pad rows: v==0 -> 0
                    Hout[(size_t)(e * T_TOK + m0 + mbase + r) * HID + n] = f2bf(v);
                } else {
                    if (ids[r] != DUMP_ID)
                        Pout[(size_t)ids[r] * DMODEL + n] = v;   // plain store
                }
            }
        }
    }
}

// ------------------------------------------------------------ combine -------
// out[t] = part[2t] + part[2t+1]   (2048 blocks x 256 thr x float4)
__global__ __launch_bounds__(256) void combine(
    const float4* __restrict__ part4, float4* __restrict__ out4) {
    int idx = blockIdx.x * 256 + threadIdx.x;     // [0, 524288)
    int t = idx >> 8;
    int d4 = idx & 255;
    float4 p0 = part4[(size_t)(2 * t) * 256 + d4];
    float4 p1 = part4[(size_t)(2 * t + 1) * 256 + d4];
    float4 o;
    o.x = p0.x + p1.x; o.y = p0.y + p1.y;
    o.z = p0.z + p1.z; o.w = p0.w + p1.w;
    out4[idx] = o;
}

// ---------------------------------------------------------------------------
extern "C" void kernel_launch(void* const* d_in, const int* in_sizes, int n_in,
                              void* d_out, int out_size, void* d_ws, size_t ws_size,
                              hipStream_t stream) {
    const float* x      = (const float*)d_in[0];
    const float* gate_w = (const float*)d_in[1];
    const float* w_up   = (const float*)d_in[2];
    const float* w_down = (const float*)d_in[3];
    const float* bias   = (const float*)d_in[4];
    float* out = (float*)d_out;

    // workspace layout (16B aligned chunks)
    char* p = (char*)d_ws;
    int* counts = (int*)p;                 p += 256;
    int* list   = (int*)p;                 p += NEXP * T_TOK * 4;
    float* w2   = (float*)p;               p += 4104 * 4;
    unsigned int* selpack = (unsigned int*)p;  p += T_TOK * 4;
    u16* xb  = (u16*)p;  p += (size_t)(T_TOK + 1) * DMODEL * 2;          // ~4 MB
    u16* h   = (u16*)p;  p += (size_t)NEXP * T_TOK * HID * 2;            // 64 MB
    float* part = (float*)p;  p += (size_t)2 * T_TOK * DMODEL * 4;       // 16 MB

    // 1. router scores + x->bf16 + dump-row init
    fused_pre<<<257, 256, 0, stream>>>(
        (const float4*)x, (const float4*)gate_w, bias,
        (ushort4*)xb, selpack, w2,
        (unsigned int*)(xb + (size_t)T_TOK * DMODEL));

    // 2. deterministic list build (no global atomics)
    build_lists<<<NEXP, 256, 0, stream>>>(selpack, counts, list);

    // 3. up-GEMM: h(position-order) = bf16( w2 * relu(x @ Wu^T)^2 )
    moe_gemm<0><<<16 * (HID / 128) * NEXP, 256, 0, stream>>>(
        xb, list, counts, w_up, w2, h, nullptr);

    // 4. down-GEMM: part[id] = h_row @ Wd^T   (plain stores, no atomics)
    moe_gemm<1><<<16 * (DMODEL / 128) * NEXP, 256, 0, stream>>>(
        h, list, counts, w_down, w2, nullptr, part);

    // 5. combine: out[t] = part[2t] + part[2t+1]
    combine<<<T_TOK * DMODEL / 4 / 256, 256, 0, stream>>>(
        (const float4*)part, (float4*)out);
}